// Round 7
// baseline (268.467 us; speedup 1.0000x reference)
//
#include <hip/hip_runtime.h>
#include <math.h>

// Blinn-Phong shading, N=4194304 elements of (light,normal,view) 3-vectors.
// Memory-bound streaming: 36 B in + 12 B out per element -> 201 MB.
// R6 finding: LDS-staged (R2) and no-LDS (R6) structures tie at ~69 us inferred
// -> limiter is external: harness restore/poison writebacks drain inside our
// window (R5 counters: window WRITE = restore+out exactly), ~335 MB real
// traffic ~ 4.9 TB/s aggregate.
// R7: nontemporal (nt) loads+stores -> no-allocate streaming; avoid evicting
// the harness's dirty L2/L3 lines (forced writeback-refetch serialization)
// and avoid dirtying L2 with our own 49 MB output.
// Math: v_rsq via max(sqrt(hh),EPS)==sqrt(max(hh,EPS^2));
//   powf -> v_log_f32/v_exp_f32 (__builtin_amdgcn_{logf,exp2f}; exact at nh=0).

#define BLOCK 256
#define EPT 4   // elements per thread; 4*9 floats = 9 float4, 4*3 = 3 float4

typedef float v4f __attribute__((ext_vector_type(4)));

__global__ __launch_bounds__(BLOCK) void blinn_phong_kernel(
    const float* __restrict__ in,   // (n, 3, 3)
    const float* __restrict__ kd,   // (3,)
    const float* __restrict__ ks,   // (3,)
    const float* __restrict__ pp,   // (1,)
    float* __restrict__ out,        // (n, 3)
    int n)
{
    const long long g = (long long)blockIdx.x * BLOCK + threadIdx.x;
    const long long e0 = g * EPT;
    if (e0 >= n) return;            // n % 4 == 0 -> whole thread in/out of bounds

    const v4f* __restrict__ gin4 = (const v4f*)in;
    v4f* __restrict__ gout4 = (v4f*)out;

    // ---- 9 contiguous nt float4 loads (144 B per lane), all independent ----
    v4f r[9];
    const long long ib = g * 9;
#pragma unroll
    for (int i = 0; i < 9; ++i) r[i] = __builtin_nontemporal_load(&gin4[ib + i]);
    const float* f = (const float*)r;   // f[9m + k]: element m, component k

    const float kd0 = kd[0], kd1 = kd[1], kd2 = kd[2];
    const float ks0 = ks[0], ks1 = ks[1], ks2 = ks[2];
    const float p = pp[0];

    v4f o[3];
    float* ov = (float*)o;              // 12 output floats

#pragma unroll
    for (int m = 0; m < EPT; ++m) {
        const float Lx = f[9*m+0], Ly = f[9*m+1], Lz = f[9*m+2];
        const float Nx = f[9*m+3], Ny = f[9*m+4], Nz = f[9*m+5];
        const float Vx = f[9*m+6], Vy = f[9*m+7], Vz = f[9*m+8];

        const float ln = fmaxf(0.0f, Lx * Nx + Ly * Ny + Lz * Nz);

        const float hx = Lx + Vx, hy = Ly + Vy, hz = Lz + Vz;
        const float hh = hx * hx + hy * hy + hz * hz;
        const float inv = rsqrtf(fmaxf(hh, 1e-24f));   // single v_rsq_f32

        const float nh = fmaxf(0.0f, (Nx * hx + Ny * hy + Nz * hz) * inv);
        // nh >= 0; v_log_f32(0) = -inf -> v_exp_f32(-inf) = 0 == 0^p
        const float spec = __builtin_amdgcn_exp2f(p * __builtin_amdgcn_logf(nh));

        ov[3*m + 0] = ks0 * spec + kd0 * ln;
        ov[3*m + 1] = ks1 * spec + kd1 * ln;
        ov[3*m + 2] = ks2 * spec + kd2 * ln;
    }

    // ---- 3 contiguous nt float4 stores (48 B per lane) ----
    const long long ob = g * 3;
#pragma unroll
    for (int m = 0; m < 3; ++m) __builtin_nontemporal_store(o[m], &gout4[ob + m]);
}

extern "C" void kernel_launch(void* const* d_in, const int* in_sizes, int n_in,
                              void* d_out, int out_size, void* d_ws, size_t ws_size,
                              hipStream_t stream) {
    const float* in = (const float*)d_in[0];
    const float* kd = (const float*)d_in[1];
    const float* ks = (const float*)d_in[2];
    const float* pp = (const float*)d_in[3];
    float* out = (float*)d_out;

    int n = in_sizes[0] / 9;
    int threads_needed = (n + EPT - 1) / EPT;
    int grid = (threads_needed + BLOCK - 1) / BLOCK;
    blinn_phong_kernel<<<grid, BLOCK, 0, stream>>>(in, kd, ks, pp, out, n);
}